// Round 4
// baseline (326.551 us; speedup 1.0000x reference)
//
#include <hip/hip_runtime.h>

// ---------------------------------------------------------------------------
// UFO linear attention: qkv = x@Wqkv; kv = k^T v per head; xnorm(kv), xnorm(q);
// out = q_n @ kv_n; final = out @ W_o + b_o.
// B=4, N=4096, DIM=1024, H=16, Dh=64.  All big matmuls in bf16 MFMA.
// R2: q-norm fused into GEMM1 epilogue; R5: fold Wo into kvn (Mt per batch).
// R6: NEVER pass min-waves arg on MFMA kernels with 64-reg accumulators.
// R7: 256x256 counted-vmcnt pipeline: 869 TF, MfmaUtil 38%.
// R8: -sched_barrier, +T1 XCD swizzle: FETCH 152->94MB, MfmaUtil still 38%.
// R9: BK=64 k-slice dbuf, 2 barriers/tile: 969 TF, MfmaUtil 40%.
//     LDS-BW check: 36 B/cyc/CU used << 128 peak -> NOT LDS-bound; the
//     exposed ds_read latency (reads after barrier, no rendezvous) is the gap.
// R10: m201 phase rhythm, one variable vs R9: 4 phases/tile, each
//     {ds_read subtile -> stage half-slice -> [vmcnt(4) @P1/P3] -> s_barrier
//      -> lgkmcnt(0) -> setprio(1) -> 16 MFMA -> setprio(0) -> s_barrier}.
//     Reads issue BEFORE the rendezvous barrier (latency hides under it);
//     double-barrier per phase creates the wave role-split T5 needs (m218b).
//     Same stage->consume mapping as R9 (race-free, residency fenced one
//     phase ahead; every LDS WAR pair barrier-separated).
// ---------------------------------------------------------------------------

typedef __bf16 bf16;
typedef bf16  bf16x8 __attribute__((ext_vector_type(8)));
typedef bf16  bf16x4 __attribute__((ext_vector_type(4)));
typedef float f32x4  __attribute__((ext_vector_type(4)));

#define BATCH   4
#define SEQ     4096
#define DIM     1024
#define HEADS   16
#define DHEAD   64
#define MTOK    (BATCH*SEQ)          // 16384
#define N_QKV   (3*DIM)              // 3072
#define NSPLIT  16                   // kv einsum n-splits

#define NB_PACK (MTOK*DIM/(8*256))   // 8192
#define NB_T1   ((N_QKV/32)*(DIM/32))// 3072
#define NB_T2   ((DIM/32)*(DIM/32))  // 1024

typedef __attribute__((address_space(1))) const void gas_v;
typedef __attribute__((address_space(3))) void las_v;

__device__ __forceinline__ void gld_lds16(const void* g, void* l) {
  __builtin_amdgcn_global_load_lds((gas_v*)g, (las_v*)l, 16, 0, 0);
}

template <int VMN>
__device__ __forceinline__ void vmwait() {
  if constexpr (VMN == 4) asm volatile("s_waitcnt vmcnt(4)" ::: "memory");
  else if constexpr (VMN == 0) asm volatile("s_waitcnt vmcnt(0)" ::: "memory");
}

// ---------------------------------------------------------------------------
// prep: [0,8192) pack x->bf16 ; [8192,11264) transpose Wqkv ; rest Wo.
// ---------------------------------------------------------------------------
__global__ __launch_bounds__(256) void prep(const float* __restrict__ x,
                                            const float* __restrict__ Wqkv,
                                            const float* __restrict__ Wo,
                                            bf16* __restrict__ xb,
                                            bf16* __restrict__ WqT,
                                            bf16* __restrict__ WoT) {
  const int bid = blockIdx.x;
  const int t   = threadIdx.x;
  if (bid < NB_PACK) {
    size_t i = (size_t)bid * 256 + t;
    f32x4 a = *(const f32x4*)&x[i * 8];
    f32x4 b = *(const f32x4*)&x[i * 8 + 4];
    bf16x8 o = {(bf16)a.x, (bf16)a.y, (bf16)a.z, (bf16)a.w,
                (bf16)b.x, (bf16)b.y, (bf16)b.z, (bf16)b.w};
    *(bf16x8*)&xb[i * 8] = o;
    return;
  }
  __shared__ float tile[32][33];
  const float* in; bf16* out; int R, C, bx, by;
  if (bid < NB_PACK + NB_T1) {
    int tid = bid - NB_PACK;
    in = Wqkv; out = WqT; R = DIM; C = N_QKV;
    bx = tid % (N_QKV / 32); by = tid / (N_QKV / 32);
  } else {
    int tid = bid - NB_PACK - NB_T1;
    in = Wo; out = WoT; R = DIM; C = DIM;
    bx = tid & 31; by = tid >> 5;
  }
  int c0 = bx * 32, r0 = by * 32;
  int tx = t & 31, ty = t >> 5;    // 32 x 8
#pragma unroll
  for (int i = 0; i < 32; i += 8)
    tile[ty + i][tx] = in[(size_t)(r0 + ty + i) * C + c0 + tx];
  __syncthreads();
#pragma unroll
  for (int i = 0; i < 32; i += 8)
    out[(size_t)(c0 + ty + i) * R + r0 + tx] = (bf16)tile[tx][ty + i];
}

// ---------------------------------------------------------------------------
// gemm256: C[M,N] = A[M,K] * Bt[N,K]^T  (bf16 in, fp32 acc).
// 256x256 tile, BK=64, 512 thr (8 waves as 2Mx4N), 2-dbuf k-slice LDS
// (128 KiB), 4 phases/K-tile (m201 rhythm), vmcnt(4) at P1/P3.
// MODE 1: qkv GEMM; q -> fused xnorm -> bf16 qn; k,v -> bf16.
// MODE 2: final GEMM; Bt is per-batch (Mt_b), +bias, fp32 out.
// ---------------------------------------------------------------------------
template <int MODE>
__global__ __launch_bounds__(512) void gemm256(
    const bf16* __restrict__ A, const bf16* __restrict__ Bt, int N, int K,
    float* __restrict__ C, const float* __restrict__ bias,
    const float* __restrict__ gamma,
    bf16* __restrict__ qn, bf16* __restrict__ kb, bf16* __restrict__ vb) {
  // [dbuf][op A/B][k-slice][256 rows x 32 k]  = 128 KiB
  __shared__ bf16 lds[2][2][2][256 * 32];
  const int t    = threadIdx.x;
  const int lane = t & 63;
  const int wv   = t >> 6;        // 8 waves
  const int wr   = wv >> 2;       // 0..1  -> rows wr*128..+128
  const int wc   = wv & 3;        // 0..3  -> cols wc*64..+64

  // T1: bijective XCD-chunked swizzle (nwg % 8 == 0 for both grids).
  const int GX  = gridDim.x;
  const int nwg = GX * gridDim.y;
  int lin = blockIdx.y * GX + blockIdx.x;
  lin = (lin & 7) * (nwg >> 3) + (lin >> 3);
  const int m0 = (lin / GX) * 256;
  const int n0 = (lin % GX) * 256;

  const int lr   = lane & 15;     // row within 16x16 tile
  const int ks   = lane >> 4;     // 8-elem k-chunk within 32-k slice

  if (MODE == 2) Bt += (size_t)(m0 >> 12) * DIM * DIM;   // per-batch fold

  // fragment LDS offsets within a slice (chunk ^= (row>>1)&3 on 16B chunks)
  int aoff[8], boff[4];
#pragma unroll
  for (int i = 0; i < 8; i++) {
    int ra  = wr * 128 + i * 16 + lr;
    aoff[i] = ra * 32 + ((ks ^ ((ra >> 1) & 3)) * 8);
  }
#pragma unroll
  for (int j = 0; j < 4; j++) {
    int rb  = wc * 64 + j * 16 + lr;
    boff[j] = rb * 32 + ((ks ^ ((rb >> 1) & 3)) * 8);
  }

  const bf16* Asrc = A;
  const bf16* Bsrc = Bt;
  // stage one 256x32 half-slice (16 KB): 2 gld_lds16 per thread
  auto stage = [&](int op, int sl, int bufi, int tt) {
    const bf16* src = op ? Bsrc : Asrc;
    const int   rb0 = op ? n0 : m0;
    const int   k0  = tt * 64 + sl * 32;
#pragma unroll
    for (int p = 0; p < 2; ++p) {
      int row  = p * 128 + (t >> 2);
      int gseg = (t & 3) ^ ((row >> 1) & 3);
      gld_lds16(src + (size_t)(rb0 + row) * K + k0 + gseg * 8,
                &lds[bufi][op][sl][row * 32 + (t & 3) * 8]);
    }
  };

  f32x4 acc[8][4];
#pragma unroll
  for (int i = 0; i < 8; i++)
#pragma unroll
    for (int j = 0; j < 4; j++) acc[i][j] = {0.f, 0.f, 0.f, 0.f};

  bf16x8 af[4], bfv[4];

// One phase (m201 rhythm): quadrant (IH half of i, KK k-slice) of buf BB.
// ds_read subtile (8 b128 when IH==0: B+A; else 4: A only) -> stage one
// half-slice of tile STT into BB^1 -> optional vmcnt -> barrier ->
// lgkmcnt(0) -> setprio(1) -> 16 MFMA -> setprio(0) -> barrier.
#define PH(IH, KK, BB, DOST, SOP, SSL, STT, VM)                               \
  {                                                                           \
    const bf16* sA = &lds[BB][0][KK][0];                                      \
    const bf16* sB = &lds[BB][1][KK][0];                                      \
    if ((IH) == 0) {                                                          \
      _Pragma("unroll") for (int j = 0; j < 4; j++)                           \
          bfv[j] = *(const bf16x8*)&sB[boff[j]];                              \
    }                                                                         \
    _Pragma("unroll") for (int i = 0; i < 4; i++)                             \
        af[i] = *(const bf16x8*)&sA[aoff[(IH) * 4 + i]];                      \
    if (DOST) stage(SOP, SSL, (BB) ^ 1, STT);                                 \
    vmwait<VM>();                                                             \
    __builtin_amdgcn_s_barrier();                                             \
    asm volatile("s_waitcnt lgkmcnt(0)" ::: "memory");                        \
    __builtin_amdgcn_s_setprio(1);                                            \
    _Pragma("unroll") for (int i = 0; i < 4; i++)                             \
      _Pragma("unroll") for (int j = 0; j < 4; j++)                           \
          acc[(IH) * 4 + i][j] = __builtin_amdgcn_mfma_f32_16x16x32_bf16(     \
              af[i], bfv[j], acc[(IH) * 4 + i][j], 0, 0, 0);                  \
    __builtin_amdgcn_s_setprio(0);                                            \
    __builtin_amdgcn_s_barrier();                                             \
  }

  const int NT = K >> 6;          // K/64
  // prologue: stage tile 0 (A-k0, B-k0, A-k1, B-k1); k0 resident after
  // vmcnt(4); k1 fenced at P1 of tile 0.
  stage(0, 0, 0, 0); stage(1, 0, 0, 0);
  stage(0, 1, 0, 0); stage(1, 1, 0, 0);
  vmwait<4>();
  __builtin_amdgcn_s_barrier();

  for (int tt = 0; tt < NT - 1; ++tt) {
    const int bb = tt & 1;
    // vmcnt ledger (steady state): enter tile with 4 outstanding (k1(t)).
    PH(0, 0, bb, 1, 0, 0, tt + 1, -1);  // P0: +A-k0(t+1) -> 6
    PH(1, 0, bb, 1, 1, 0, tt + 1, 4);   // P1: +B-k0(t+1) -> 8; vm4 drains k1(t)
    PH(0, 1, bb, 1, 0, 1, tt + 1, -1);  // P2: +A-k1(t+1) -> 6
    PH(1, 1, bb, 1, 1, 1, tt + 1, 4);   // P3: +B-k1(t+1) -> 8; vm4 drains k0(t+1)
  }
  {                                     // final tile: no stages
    const int bb = (NT - 1) & 1;
    PH(0, 0, bb, 0, 0, 0, 0, -1);
    PH(1, 0, bb, 0, 0, 0, 0, 0);        // drain k1(NT-1)
    PH(0, 1, bb, 0, 0, 0, 0, -1);
    PH(1, 1, bb, 0, 0, 0, 0, -1);
  }
#undef PH

  // epilogue: C layout col=lane&15, row=(lane>>4)*4+reg  (m89-verified)
  const int crow0 = m0 + wr * 128 + (lane >> 4) * 4;

  if (MODE == 2) {
    const int ccol0 = n0 + wc * 64 + lr;
#pragma unroll
    for (int i = 0; i < 8; i++)
#pragma unroll
      for (int j = 0; j < 4; j++) {
        int col = ccol0 + j * 16;
#pragma unroll
        for (int r = 0; r < 4; r++)
          C[(size_t)(crow0 + i * 16 + r) * N + col] = acc[i][j][r] + bias[col];
      }
  } else {
    const int seg = n0 >> 10;           // block-uniform: 0=q, 1=k, 2=v
    if (seg == 0) {
      // fused q-norm: this wave's 64 cols are exactly head h
      const int h    = (n0 + wc * 64) >> 6;
      const float g  = gamma[h];
      const int col0 = n0 + wc * 64 + lr;
#pragma unroll
      for (int i = 0; i < 8; i++)
#pragma unroll
        for (int r = 0; r < 4; r++) {
          float p = acc[i][0][r] * acc[i][0][r] + acc[i][1][r] * acc[i][1][r]
                  + acc[i][2][r] * acc[i][2][r] + acc[i][3][r] * acc[i][3][r];
          p += __shfl_xor(p, 1);
          p += __shfl_xor(p, 2);
          p += __shfl_xor(p, 4);
          p += __shfl_xor(p, 8);        // 16 lanes = the head's 64 cols
          float sc = g * rsqrtf(p);
          size_t rb = (size_t)(crow0 + i * 16 + r) * DIM + col0;
#pragma unroll
          for (int j = 0; j < 4; j++)
            qn[rb + j * 16] = (bf16)(acc[i][j][r] * sc);
        }
    } else {
      bf16* dst = (seg == 1) ? kb : vb;
      const int ccol0 = (n0 - (seg << 10)) + wc * 64 + lr;
#pragma unroll
      for (int i = 0; i < 8; i++)
#pragma unroll
        for (int j = 0; j < 4; j++) {
          int col = ccol0 + j * 16;
#pragma unroll
          for (int r = 0; r < 4; r++)
            dst[(size_t)(crow0 + i * 16 + r) * DIM + col] = (bf16)acc[i][j][r];
        }
    }
  }
}

// ---------------------------------------------------------------------------
// kv partials. grid (NSPLIT, 64bh). fp32 outer-product, 4x4 acc/thread.
// ---------------------------------------------------------------------------
__global__ __launch_bounds__(256) void kv_partial(const bf16* __restrict__ kb,
                                                  const bf16* __restrict__ vb,
                                                  float* __restrict__ part) {
  __shared__ float lK[32 * 64];
  __shared__ float lV[32 * 64];
  const int t  = threadIdx.x;
  const int s  = blockIdx.x;
  const int bh = blockIdx.y;
  const int b  = bh >> 4, h = bh & 15;
  const size_t base = ((size_t)b * SEQ + s * (SEQ / NSPLIT)) * DIM + h * DHEAD;
  const int d0 = (t & 15) * 4, e0 = (t >> 4) * 4;
  const int rr = t >> 3, cc = (t & 7) * 8;

  float acc[4][4];
#pragma unroll
  for (int a = 0; a < 4; a++)
#pragma unroll
    for (int q = 0; q < 4; q++) acc[a][q] = 0.f;

  for (int nt = 0; nt < (SEQ / NSPLIT) / 32; nt++) {
    size_t g = base + (size_t)(nt * 32 + rr) * DIM + cc;
    bf16x8 k8 = *(const bf16x8*)(kb + g);
    bf16x8 v8 = *(const bf16x8*)(vb + g);
    f32x4 klo = {(float)k8[0], (float)k8[1], (float)k8[2], (float)k8[3]};
    f32x4 khi = {(float)k8[4], (float)k8[5], (float)k8[6], (float)k8[7]};
    f32x4 vlo = {(float)v8[0], (float)v8[1], (float)v8[2], (float)v8[3]};
    f32x4 vhi = {(float)v8[4], (float)v8[5], (float)v8[6], (float)v8[7]};
    *(f32x4*)&lK[rr * 64 + cc]     = klo;
    *(f32x4*)&lK[rr * 64 + cc + 4] = khi;
    *(f32x4*)&lV[rr * 64 + cc]     = vlo;
    *(f32x4*)&lV[rr * 64 + cc + 4] = vhi;
    __syncthreads();
#pragma unroll 8
    for (int nn = 0; nn < 32; nn++) {
      f32x4 kk = *(const f32x4*)&lK[nn * 64 + d0];
      f32x4 vv = *(const f32x4*)&lV[nn * 64 + e0];
#pragma unroll
      for (int a = 0; a < 4; a++)
#pragma unroll
        for (int q = 0; q < 4; q++) acc[a][q] += kk[a] * vv[q];
    }
    __syncthreads();
  }
  float* pb = part + ((size_t)bh * NSPLIT + s) * 4096;
#pragma unroll
  for (int a = 0; a < 4; a++) {
    f32x4 o = {acc[a][0], acc[a][1], acc[a][2], acc[a][3]};
    *(f32x4*)&pb[(d0 + a) * 64 + e0] = o;
  }
}

// ---------------------------------------------------------------------------
// kv_norm: reduce partials, row-norm over e, write kvn[bh][d][e] bf16
// ---------------------------------------------------------------------------
__global__ __launch_bounds__(256) void kv_norm(const float* __restrict__ part,
                                               const float* __restrict__ gamma,
                                               bf16* __restrict__ kvn) {
  const int t   = threadIdx.x;
  const int bh  = blockIdx.x >> 2;
  const int h   = bh & 15;
  const int d   = (blockIdx.x & 3) * 16 + (t >> 4);
  const int e0  = (t & 15) * 4;
  f32x4 v = {0.f, 0.f, 0.f, 0.f};
  for (int s = 0; s < NSPLIT; s++) {
    f32x4 a = *(const f32x4*)(part + ((size_t)bh * NSPLIT + s) * 4096 + d * 64 + e0);
    v.x += a.x; v.y += a.y; v.z += a.z; v.w += a.w;
  }
  float ss = v.x * v.x + v.y * v.y + v.z * v.z + v.w * v.w;
  ss += __shfl_xor(ss, 1);
  ss += __shfl_xor(ss, 2);
  ss += __shfl_xor(ss, 4);
  ss += __shfl_xor(ss, 8);          // 16 consecutive lanes share d
  float scale = gamma[h] * rsqrtf(ss);
  bf16x4 o = {(bf16)(v.x * scale), (bf16)(v.y * scale),
              (bf16)(v.z * scale), (bf16)(v.w * scale)};
  *(bf16x4*)&kvn[(size_t)bh * 4096 + d * 64 + e0] = o;
}

// ---------------------------------------------------------------------------
// mfold: Mt[b][n][h*64+d] = sum_e WoT[n][h*64+e] * kvn[bh][d][e]
// ---------------------------------------------------------------------------
__global__ __launch_bounds__(256) void mfold(const bf16* __restrict__ WoT,
                                             const bf16* __restrict__ kvn,
                                             bf16* __restrict__ Mt) {
  __shared__ bf16 lA[128 * 64];   // WoT tile: 128 n-rows x 64 e
  __shared__ bf16 lB[64 * 64];    // kvn_h: 64 d x 64 e
  const int t    = threadIdx.x;
  const int lane = t & 63;
  const int wv   = t >> 6;
  const int bh   = blockIdx.y;
  const int b    = bh >> 4, h = bh & 15;
  const int n0   = blockIdx.x * 128;

#pragma unroll
  for (int p = 0; p < 4; p++) {
    int c = p * 256 + t;
    int row = c >> 3, seg = c & 7;
    int gsk = seg ^ (row & 7);
    gld_lds16(WoT + (size_t)(n0 + row) * DIM + h * 64 + gsk * 8,
              &lA[row * 64 + seg * 8]);
  }
#pragma unroll
  for (int p = 0; p < 2; p++) {
    int c = p * 256 + t;
    int row = c >> 3, seg = c & 7;
    int gsk = seg ^ (row & 7);
    gld_lds16(kvn + (size_t)bh * 4096 + row * 64 + gsk * 8,
              &lB[row * 64 + seg * 8]);
  }
  __syncthreads();

  const int lr = lane & 15, ks = lane >> 4;
  f32x4 acc[2][4];
#pragma unroll
  for (int i = 0; i < 2; i++)
#pragma unroll
    for (int j = 0; j < 4; j++) acc[i][j] = {0.f, 0.f, 0.f, 0.f};

#pragma unroll
  for (int kk = 0; kk < 2; kk++) {
    bf16x8 af[2], bkv[4];
#pragma unroll
    for (int i = 0; i < 2; i++) {
      int row = wv * 32 + i * 16 + lr;
      int seg = (kk * 4 + ks) ^ (row & 7);
      af[i] = *(const bf16x8*)&lA[row * 64 + seg * 8];
    }
#pragma unroll
    for (int j = 0; j < 4; j++) {
      int row = j * 16 + lr;
      int seg = (kk * 4 + ks) ^ (row & 7);
      bkv[j] = *(const bf16x8*)&lB[row * 64 + seg * 8];
    }
#pragma unroll
    for (int i = 0; i < 2; i++)
#pragma unroll
      for (int j = 0; j < 4; j++)
        acc[i][j] = __builtin_amdgcn_mfma_f32_16x16x32_bf16(af[i], bkv[j],
                                                            acc[i][j], 0, 0, 0);
  }

  // C layout: row(n) = wv*32 + i*16 + ks*4 + r ; col(d) = j*16 + lr
  bf16* mb = Mt + (size_t)b * DIM * DIM;
#pragma unroll
  for (int i = 0; i < 2; i++)
#pragma unroll
    for (int j = 0; j < 4; j++) {
      int col = h * 64 + j * 16 + lr;
#pragma unroll
      for (int r = 0; r < 4; r++) {
        int row = n0 + wv * 32 + i * 16 + ks * 4 + r;
        mb[(size_t)row * DIM + col] = (bf16)acc[i][j][r];
      }
    }
}

// ---------------------------------------------------------------------------
extern "C" void kernel_launch(void* const* d_in, const int* in_sizes, int n_in,
                              void* d_out, int out_size, void* d_ws,
                              size_t ws_size, hipStream_t stream) {
  const float* x     = (const float*)d_in[0];
  const float* Wqkv  = (const float*)d_in[1];
  const float* Wo    = (const float*)d_in[2];
  const float* bo    = (const float*)d_in[3];
  const float* gamma = (const float*)d_in[4];
  float* out = (float*)d_out;

  char* ws = (char*)d_ws;
  size_t off = 0;
  bf16*  xb   = (bf16*)(ws + off);  off += (size_t)MTOK * DIM * 2;        // 32 MB
  bf16*  WqT  = (bf16*)(ws + off);  off += (size_t)N_QKV * DIM * 2;       //  6 MB
  bf16*  WoT  = (bf16*)(ws + off);  off += (size_t)DIM * DIM * 2;         //  2 MB
  bf16*  kvn  = (bf16*)(ws + off);  off += (size_t)64 * 4096 * 2;         // .5 MB
  bf16*  qn   = (bf16*)(ws + off);  off += (size_t)MTOK * DIM * 2;        // 32 MB
  bf16*  kb   = (bf16*)(ws + off);  off += (size_t)MTOK * DIM * 2;        // 32 MB
  bf16*  vb   = (bf16*)(ws + off);  off += (size_t)MTOK * DIM * 2;        // 32 MB
  float* part = (float*)(ws + off); off += (size_t)64 * NSPLIT * 4096 * 4;// 16 MB
  bf16*  Mt   = (bf16*)(ws + off);  off += (size_t)BATCH * DIM * DIM * 2; //  8 MB

  prep<<<dim3(NB_PACK + NB_T1 + NB_T2), dim3(256), 0, stream>>>(
      x, Wqkv, Wo, xb, WqT, WoT);

  gemm256<1><<<dim3(N_QKV / 256, MTOK / 256), dim3(512), 0, stream>>>(
      xb, WqT, N_QKV, DIM, nullptr, nullptr, gamma, qn, kb, vb);

  kv_partial<<<dim3(NSPLIT, 64), dim3(256), 0, stream>>>(kb, vb, part);
  kv_norm<<<dim3(256), dim3(256), 0, stream>>>(part, gamma, kvn);

  mfold<<<dim3(DIM / 128, 64), dim3(256), 0, stream>>>(WoT, kvn, Mt);

  gemm256<2><<<dim3(DIM / 256, MTOK / 256), dim3(512), 0, stream>>>(
      qn, Mt, DIM, DIM, out, bo, nullptr, nullptr, nullptr, nullptr);
}

// Round 5
// 324.862 us; speedup vs baseline: 1.0052x; 1.0052x over previous
//
#include <hip/hip_runtime.h>

// ---------------------------------------------------------------------------
// UFO linear attention: qkv = x@Wqkv; kv = k^T v per head; xnorm(kv), xnorm(q);
// out = q_n @ kv_n; final = out @ W_o + b_o.
// B=4, N=4096, DIM=1024, H=16, Dh=64.  All big matmuls in bf16 MFMA.
// R2: q-norm fused into GEMM1 epilogue; R5: fold Wo into kvn (Mt per batch).
// R6: never starve MFMA kernels with aggressive min-waves VGPR caps.
// R7-R10: 256x256 1-block/CU schedules all pin at 38-41% MfmaUtil (~970 TF):
//     4-ring counted vmcnt (869), -schedbar +XCD swz (FETCH 152->94MB), BK=64
//     k-slice dbuf (969), m201 phase rhythm (regressed). Schedule theory dead:
//     with 1 block/CU every barrier idles the whole CU.
// R11: TLP instead: tile 256x128, BK=32, ring-3 LDS = 72 KiB -> 2 blocks/CU,
//     acc 64 VGPR, launch_bounds(512,4) caps VGPR at 128 (est ~120, no spill)
//     so 16 waves/CU co-schedule; cross-block overlap fills barrier idle
//     (m114 mechanism). Phase: {8 ds_read, stage t+2 (3 gld), vmcnt(3), bar,
//     lgkmcnt(0), 16 MFMA}. Ring-3: stage->consume distance 2 phases; all
//     LDS WAR pairs barrier-separated; vmcnt(3)@t retires tile t+1.
// ---------------------------------------------------------------------------

typedef __bf16 bf16;
typedef bf16  bf16x8 __attribute__((ext_vector_type(8)));
typedef bf16  bf16x4 __attribute__((ext_vector_type(4)));
typedef float f32x4  __attribute__((ext_vector_type(4)));

#define BATCH   4
#define SEQ     4096
#define DIM     1024
#define HEADS   16
#define DHEAD   64
#define MTOK    (BATCH*SEQ)          // 16384
#define N_QKV   (3*DIM)              // 3072
#define NSPLIT  16                   // kv einsum n-splits

#define NB_PACK (MTOK*DIM/(8*256))   // 8192
#define NB_T1   ((N_QKV/32)*(DIM/32))// 3072
#define NB_T2   ((DIM/32)*(DIM/32))  // 1024

typedef __attribute__((address_space(1))) const void gas_v;
typedef __attribute__((address_space(3))) void las_v;

__device__ __forceinline__ void gld_lds16(const void* g, void* l) {
  __builtin_amdgcn_global_load_lds((gas_v*)g, (las_v*)l, 16, 0, 0);
}

template <int VMN>
__device__ __forceinline__ void vmwait() {
  if constexpr (VMN == 3)      asm volatile("s_waitcnt vmcnt(3)" ::: "memory");
  else if constexpr (VMN == 0) asm volatile("s_waitcnt vmcnt(0)" ::: "memory");
}

// ---------------------------------------------------------------------------
// prep: [0,8192) pack x->bf16 ; [8192,11264) transpose Wqkv ; rest Wo.
// ---------------------------------------------------------------------------
__global__ __launch_bounds__(256) void prep(const float* __restrict__ x,
                                            const float* __restrict__ Wqkv,
                                            const float* __restrict__ Wo,
                                            bf16* __restrict__ xb,
                                            bf16* __restrict__ WqT,
                                            bf16* __restrict__ WoT) {
  const int bid = blockIdx.x;
  const int t   = threadIdx.x;
  if (bid < NB_PACK) {
    size_t i = (size_t)bid * 256 + t;
    f32x4 a = *(const f32x4*)&x[i * 8];
    f32x4 b = *(const f32x4*)&x[i * 8 + 4];
    bf16x8 o = {(bf16)a.x, (bf16)a.y, (bf16)a.z, (bf16)a.w,
                (bf16)b.x, (bf16)b.y, (bf16)b.z, (bf16)b.w};
    *(bf16x8*)&xb[i * 8] = o;
    return;
  }
  __shared__ float tile[32][33];
  const float* in; bf16* out; int R, C, bx, by;
  if (bid < NB_PACK + NB_T1) {
    int tid = bid - NB_PACK;
    in = Wqkv; out = WqT; R = DIM; C = N_QKV;
    bx = tid % (N_QKV / 32); by = tid / (N_QKV / 32);
  } else {
    int tid = bid - NB_PACK - NB_T1;
    in = Wo; out = WoT; R = DIM; C = DIM;
    bx = tid & 31; by = tid >> 5;
  }
  int c0 = bx * 32, r0 = by * 32;
  int tx = t & 31, ty = t >> 5;    // 32 x 8
#pragma unroll
  for (int i = 0; i < 32; i += 8)
    tile[ty + i][tx] = in[(size_t)(r0 + ty + i) * C + c0 + tx];
  __syncthreads();
#pragma unroll
  for (int i = 0; i < 32; i += 8)
    out[(size_t)(c0 + ty + i) * R + r0 + tx] = (bf16)tile[tx][ty + i];
}

// ---------------------------------------------------------------------------
// gemm256: C[M,N] = A[M,K] * Bt[N,K]^T  (bf16 in, fp32 acc).
// 256x128 tile, BK=32, 512 thr (8 waves as 4Mx2N, 64x64 each), ring-3 LDS
// (72 KiB -> 2 blocks/CU), counted vmcnt(3), 1 barrier/phase.
// MODE 1: qkv GEMM; q -> fused xnorm -> bf16 qn; k,v -> bf16.
// MODE 2: final GEMM; Bt is per-batch (Mt_b), +bias, fp32 out.
// ---------------------------------------------------------------------------
template <int MODE>
__global__ __launch_bounds__(512, 4) void gemm256(
    const bf16* __restrict__ A, const bf16* __restrict__ Bt, int N, int K,
    float* __restrict__ C, const float* __restrict__ bias,
    const float* __restrict__ gamma,
    bf16* __restrict__ qn, bf16* __restrict__ kb, bf16* __restrict__ vb) {
  __shared__ bf16 lA[3][256 * 32];   // 48 KiB
  __shared__ bf16 lB[3][128 * 32];   // 24 KiB
  const int t    = threadIdx.x;
  const int lane = t & 63;
  const int wv   = t >> 6;        // 8 waves
  const int wr   = wv >> 1;       // 0..3  -> rows wr*64..+64
  const int wc   = wv & 1;        // 0..1  -> cols wc*64..+64

  // T1: bijective XCD-chunked swizzle (nwg % 8 == 0 for both grids).
  const int GX  = gridDim.x;
  const int nwg = GX * gridDim.y;
  int lin = blockIdx.y * GX + blockIdx.x;
  lin = (lin & 7) * (nwg >> 3) + (lin >> 3);
  const int m0 = (lin / GX) * 256;
  const int n0 = (lin % GX) * 128;

  const int lr   = lane & 15;     // row within 16x16 tile
  const int ks   = lane >> 4;     // 8-elem k-chunk of the 32-k slice

  if (MODE == 2) Bt += (size_t)(m0 >> 12) * DIM * DIM;   // per-batch fold

  // fragment LDS offsets (swizzle: chunk ^= (row>>1)&3, on 16B chunks)
  int aoff[4], boff[4];
#pragma unroll
  for (int i = 0; i < 4; i++) {
    int ra  = wr * 64 + i * 16 + lr;
    aoff[i] = ra * 32 + ((ks ^ ((ra >> 1) & 3)) * 8);
  }
#pragma unroll
  for (int j = 0; j < 4; j++) {
    int rb  = wc * 64 + j * 16 + lr;
    boff[j] = rb * 32 + ((ks ^ ((rb >> 1) & 3)) * 8);
  }

  const bf16* Asrc = A;
  const bf16* Bsrc = Bt;
  // stage K-tile tt into ring slot bufi: A 256x32 (2 gld) + B 128x32 (1 gld)
  auto stage = [&](int bufi, int tt) {
    const int k0 = tt << 5;
#pragma unroll
    for (int p = 0; p < 2; ++p) {
      int row  = p * 128 + (t >> 2);
      int gseg = (t & 3) ^ ((row >> 1) & 3);
      gld_lds16(Asrc + (size_t)(m0 + row) * K + k0 + gseg * 8,
                &lA[bufi][row * 32 + (t & 3) * 8]);
    }
    {
      int row  = t >> 2;
      int gseg = (t & 3) ^ ((row >> 1) & 3);
      gld_lds16(Bsrc + (size_t)(n0 + row) * K + k0 + gseg * 8,
                &lB[bufi][row * 32 + (t & 3) * 8]);
    }
  };

  f32x4 acc[4][4];
#pragma unroll
  for (int i = 0; i < 4; i++)
#pragma unroll
    for (int j = 0; j < 4; j++) acc[i][j] = {0.f, 0.f, 0.f, 0.f};

  bf16x8 af[4], bfv[4];

// one phase = one K-tile: read frags from ring slot TB, stage tile STT into
// slot SB, counted vmcnt, barrier, lgkm, 16 MFMA under setprio.
// vmcnt(3)@t retires stage(t+1); phase t+1's reads come after this barrier.
// WAR: stage into SB=(t+2)%3 never collides with TB=t%3 or (t+1)%3.
#define PH(TB, DOST, SB, STT, VM)                                             \
  {                                                                           \
    const bf16* sA = &lA[TB][0];                                              \
    const bf16* sB = &lB[TB][0];                                              \
    _Pragma("unroll") for (int j = 0; j < 4; j++)                             \
        bfv[j] = *(const bf16x8*)&sB[boff[j]];                                \
    _Pragma("unroll") for (int i = 0; i < 4; i++)                             \
        af[i] = *(const bf16x8*)&sA[aoff[i]];                                 \
    if (DOST) stage(SB, STT);                                                 \
    vmwait<VM>();                                                             \
    __builtin_amdgcn_s_barrier();                                             \
    asm volatile("s_waitcnt lgkmcnt(0)" ::: "memory");                        \
    __builtin_amdgcn_s_setprio(1);                                            \
    _Pragma("unroll") for (int i = 0; i < 4; i++)                             \
      _Pragma("unroll") for (int j = 0; j < 4; j++)                           \
          acc[i][j] = __builtin_amdgcn_mfma_f32_16x16x32_bf16(                \
              af[i], bfv[j], acc[i][j], 0, 0, 0);                             \
    __builtin_amdgcn_s_setprio(0);                                            \
  }

  const int NT = K >> 5;          // 32 for K=1024; (NT-2)%3 == 0
  // prologue: stage tiles 0,1; vmcnt(3) -> tile 0 resident.
  stage(0, 0);
  stage(1, 1);
  vmwait<3>();
  __builtin_amdgcn_s_barrier();

  for (int tt = 0; tt < NT - 2; tt += 3) {
    PH(0, 1, 2, tt + 2, 3);
    PH(1, 1, 0, tt + 3, 3);
    PH(2, 1, 1, tt + 4, 3);
  }
  PH(0, 0, 0, 0, 0);              // tile NT-2 (drain last stage)
  PH(1, 0, 0, 0, -1);             // tile NT-1
#undef PH

  // epilogue: C layout col=lane&15, row=(lane>>4)*4+reg  (m89-verified)
  const int crow0 = m0 + wr * 64 + (lane >> 4) * 4;

  if (MODE == 2) {
    const int ccol0 = n0 + wc * 64 + lr;
#pragma unroll
    for (int i = 0; i < 4; i++)
#pragma unroll
      for (int j = 0; j < 4; j++) {
        int col = ccol0 + j * 16;
#pragma unroll
        for (int r = 0; r < 4; r++)
          C[(size_t)(crow0 + i * 16 + r) * N + col] = acc[i][j][r] + bias[col];
      }
  } else {
    const int seg = n0 >> 10;           // block-uniform: 0=q, 1=k, 2=v
    if (seg == 0) {
      // fused q-norm: this wave's 64 cols are exactly head h
      const int h    = (n0 + wc * 64) >> 6;
      const float g  = gamma[h];
      const int col0 = n0 + wc * 64 + lr;
#pragma unroll
      for (int i = 0; i < 4; i++)
#pragma unroll
        for (int r = 0; r < 4; r++) {
          float p = acc[i][0][r] * acc[i][0][r] + acc[i][1][r] * acc[i][1][r]
                  + acc[i][2][r] * acc[i][2][r] + acc[i][3][r] * acc[i][3][r];
          p += __shfl_xor(p, 1);
          p += __shfl_xor(p, 2);
          p += __shfl_xor(p, 4);
          p += __shfl_xor(p, 8);        // 16 lanes = the head's 64 cols
          float sc = g * rsqrtf(p);
          size_t rb = (size_t)(crow0 + i * 16 + r) * DIM + col0;
#pragma unroll
          for (int j = 0; j < 4; j++)
            qn[rb + j * 16] = (bf16)(acc[i][j][r] * sc);
        }
    } else {
      bf16* dst = (seg == 1) ? kb : vb;
      const int ccol0 = (n0 - (seg << 10)) + wc * 64 + lr;
#pragma unroll
      for (int i = 0; i < 4; i++)
#pragma unroll
        for (int j = 0; j < 4; j++) {
          int col = ccol0 + j * 16;
#pragma unroll
          for (int r = 0; r < 4; r++)
            dst[(size_t)(crow0 + i * 16 + r) * DIM + col] = (bf16)acc[i][j][r];
        }
    }
  }
}

// ---------------------------------------------------------------------------
// kv partials. grid (NSPLIT, 64bh). fp32 outer-product, 4x4 acc/thread.
// ---------------------------------------------------------------------------
__global__ __launch_bounds__(256) void kv_partial(const bf16* __restrict__ kb,
                                                  const bf16* __restrict__ vb,
                                                  float* __restrict__ part) {
  __shared__ float lK[32 * 64];
  __shared__ float lV[32 * 64];
  const int t  = threadIdx.x;
  const int s  = blockIdx.x;
  const int bh = blockIdx.y;
  const int b  = bh >> 4, h = bh & 15;
  const size_t base = ((size_t)b * SEQ + s * (SEQ / NSPLIT)) * DIM + h * DHEAD;
  const int d0 = (t & 15) * 4, e0 = (t >> 4) * 4;
  const int rr = t >> 3, cc = (t & 7) * 8;

  float acc[4][4];
#pragma unroll
  for (int a = 0; a < 4; a++)
#pragma unroll
    for (int q = 0; q < 4; q++) acc[a][q] = 0.f;

  for (int nt = 0; nt < (SEQ / NSPLIT) / 32; nt++) {
    size_t g = base + (size_t)(nt * 32 + rr) * DIM + cc;
    bf16x8 k8 = *(const bf16x8*)(kb + g);
    bf16x8 v8 = *(const bf16x8*)(vb + g);
    f32x4 klo = {(float)k8[0], (float)k8[1], (float)k8[2], (float)k8[3]};
    f32x4 khi = {(float)k8[4], (float)k8[5], (float)k8[6], (float)k8[7]};
    f32x4 vlo = {(float)v8[0], (float)v8[1], (float)v8[2], (float)v8[3]};
    f32x4 vhi = {(float)v8[4], (float)v8[5], (float)v8[6], (float)v8[7]};
    *(f32x4*)&lK[rr * 64 + cc]     = klo;
    *(f32x4*)&lK[rr * 64 + cc + 4] = khi;
    *(f32x4*)&lV[rr * 64 + cc]     = vlo;
    *(f32x4*)&lV[rr * 64 + cc + 4] = vhi;
    __syncthreads();
#pragma unroll 8
    for (int nn = 0; nn < 32; nn++) {
      f32x4 kk = *(const f32x4*)&lK[nn * 64 + d0];
      f32x4 vv = *(const f32x4*)&lV[nn * 64 + e0];
#pragma unroll
      for (int a = 0; a < 4; a++)
#pragma unroll
        for (int q = 0; q < 4; q++) acc[a][q] += kk[a] * vv[q];
    }
    __syncthreads();
  }
  float* pb = part + ((size_t)bh * NSPLIT + s) * 4096;
#pragma unroll
  for (int a = 0; a < 4; a++) {
    f32x4 o = {acc[a][0], acc[a][1], acc[a][2], acc[a][3]};
    *(f32x4*)&pb[(d0 + a) * 64 + e0] = o;
  }
}

// ---------------------------------------------------------------------------
// kv_norm: reduce partials, row-norm over e, write kvn[bh][d][e] bf16
// ---------------------------------------------------------------------------
__global__ __launch_bounds__(256) void kv_norm(const float* __restrict__ part,
                                               const float* __restrict__ gamma,
                                               bf16* __restrict__ kvn) {
  const int t   = threadIdx.x;
  const int bh  = blockIdx.x >> 2;
  const int h   = bh & 15;
  const int d   = (blockIdx.x & 3) * 16 + (t >> 4);
  const int e0  = (t & 15) * 4;
  f32x4 v = {0.f, 0.f, 0.f, 0.f};
  for (int s = 0; s < NSPLIT; s++) {
    f32x4 a = *(const f32x4*)(part + ((size_t)bh * NSPLIT + s) * 4096 + d * 64 + e0);
    v.x += a.x; v.y += a.y; v.z += a.z; v.w += a.w;
  }
  float ss = v.x * v.x + v.y * v.y + v.z * v.z + v.w * v.w;
  ss += __shfl_xor(ss, 1);
  ss += __shfl_xor(ss, 2);
  ss += __shfl_xor(ss, 4);
  ss += __shfl_xor(ss, 8);          // 16 consecutive lanes share d
  float scale = gamma[h] * rsqrtf(ss);
  bf16x4 o = {(bf16)(v.x * scale), (bf16)(v.y * scale),
              (bf16)(v.z * scale), (bf16)(v.w * scale)};
  *(bf16x4*)&kvn[(size_t)bh * 4096 + d * 64 + e0] = o;
}

// ---------------------------------------------------------------------------
// mfold: Mt[b][n][h*64+d] = sum_e WoT[n][h*64+e] * kvn[bh][d][e]
// ---------------------------------------------------------------------------
__global__ __launch_bounds__(256) void mfold(const bf16* __restrict__ WoT,
                                             const bf16* __restrict__ kvn,
                                             bf16* __restrict__ Mt) {
  __shared__ bf16 lA[128 * 64];   // WoT tile: 128 n-rows x 64 e
  __shared__ bf16 lB[64 * 64];    // kvn_h: 64 d x 64 e
  const int t    = threadIdx.x;
  const int lane = t & 63;
  const int wv   = t >> 6;
  const int bh   = blockIdx.y;
  const int b    = bh >> 4, h = bh & 15;
  const int n0   = blockIdx.x * 128;

#pragma unroll
  for (int p = 0; p < 4; p++) {
    int c = p * 256 + t;
    int row = c >> 3, seg = c & 7;
    int gsk = seg ^ (row & 7);
    gld_lds16(WoT + (size_t)(n0 + row) * DIM + h * 64 + gsk * 8,
              &lA[row * 64 + seg * 8]);
  }
#pragma unroll
  for (int p = 0; p < 2; p++) {
    int c = p * 256 + t;
    int row = c >> 3, seg = c & 7;
    int gsk = seg ^ (row & 7);
    gld_lds16(kvn + (size_t)bh * 4096 + row * 64 + gsk * 8,
              &lB[row * 64 + seg * 8]);
  }
  __syncthreads();

  const int lr = lane & 15, ks = lane >> 4;
  f32x4 acc[2][4];
#pragma unroll
  for (int i = 0; i < 2; i++)
#pragma unroll
    for (int j = 0; j < 4; j++) acc[i][j] = {0.f, 0.f, 0.f, 0.f};

#pragma unroll
  for (int kk = 0; kk < 2; kk++) {
    bf16x8 af[2], bkv[4];
#pragma unroll
    for (int i = 0; i < 2; i++) {
      int row = wv * 32 + i * 16 + lr;
      int seg = (kk * 4 + ks) ^ (row & 7);
      af[i] = *(const bf16x8*)&lA[row * 64 + seg * 8];
    }
#pragma unroll
    for (int j = 0; j < 4; j++) {
      int row = j * 16 + lr;
      int seg = (kk * 4 + ks) ^ (row & 7);
      bkv[j] = *(const bf16x8*)&lB[row * 64 + seg * 8];
    }
#pragma unroll
    for (int i = 0; i < 2; i++)
#pragma unroll
      for (int j = 0; j < 4; j++)
        acc[i][j] = __builtin_amdgcn_mfma_f32_16x16x32_bf16(af[i], bkv[j],
                                                            acc[i][j], 0, 0, 0);
  }

  // C layout: row(n) = wv*32 + i*16 + ks*4 + r ; col(d) = j*16 + lr
  bf16* mb = Mt + (size_t)b * DIM * DIM;
#pragma unroll
  for (int i = 0; i < 2; i++)
#pragma unroll
    for (int j = 0; j < 4; j++) {
      int col = h * 64 + j * 16 + lr;
#pragma unroll
      for (int r = 0; r < 4; r++) {
        int row = n0 + wv * 32 + i * 16 + ks * 4 + r;
        mb[(size_t)row * DIM + col] = (bf16)acc[i][j][r];
      }
    }
}

// ---------------------------------------------------------------------------
extern "C" void kernel_launch(void* const* d_in, const int* in_sizes, int n_in,
                              void* d_out, int out_size, void* d_ws,
                              size_t ws_size, hipStream_t stream) {
  const float* x     = (const float*)d_in[0];
  const float* Wqkv  = (const float*)d_in[1];
  const float* Wo    = (const float*)d_in[2];
  const float* bo    = (const float*)d_in[3];
  const float* gamma = (const float*)d_in[4];
  float* out = (float*)d_out;

  char* ws = (char*)d_ws;
  size_t off = 0;
  bf16*  xb   = (bf16*)(ws + off);  off += (size_t)MTOK * DIM * 2;        // 32 MB
  bf16*  WqT  = (bf16*)(ws + off);  off += (size_t)N_QKV * DIM * 2;       //  6 MB
  bf16*  WoT  = (bf16*)(ws + off);  off += (size_t)DIM * DIM * 2;         //  2 MB
  bf16*  kvn  = (bf16*)(ws + off);  off += (size_t)64 * 4096 * 2;         // .5 MB
  bf16*  qn   = (bf16*)(ws + off);  off += (size_t)MTOK * DIM * 2;        // 32 MB
  bf16*  kb   = (bf16*)(ws + off);  off += (size_t)MTOK * DIM * 2;        // 32 MB
  bf16*  vb   = (bf16*)(ws + off);  off += (size_t)MTOK * DIM * 2;        // 32 MB
  float* part = (float*)(ws + off); off += (size_t)64 * NSPLIT * 4096 * 4;// 16 MB
  bf16*  Mt   = (bf16*)(ws + off);  off += (size_t)BATCH * DIM * DIM * 2; //  8 MB

  prep<<<dim3(NB_PACK + NB_T1 + NB_T2), dim3(256), 0, stream>>>(
      x, Wqkv, Wo, xb, WqT, WoT);

  gemm256<1><<<dim3(N_QKV / 128, MTOK / 256), dim3(512), 0, stream>>>(
      xb, WqT, N_QKV, DIM, nullptr, nullptr, gamma, qn, kb, vb);

  kv_partial<<<dim3(NSPLIT, 64), dim3(256), 0, stream>>>(kb, vb, part);
  kv_norm<<<dim3(256), dim3(256), 0, stream>>>(part, gamma, kvn);

  mfold<<<dim3(DIM / 128, 64), dim3(256), 0, stream>>>(WoT, kvn, Mt);

  gemm256<2><<<dim3(DIM / 128, MTOK / 256), dim3(512), 0, stream>>>(
      qn, Mt, DIM, DIM, out, bo, nullptr, nullptr, nullptr, nullptr);
}

// Round 6
// 318.338 us; speedup vs baseline: 1.0258x; 1.0205x over previous
//
#include <hip/hip_runtime.h>

// ---------------------------------------------------------------------------
// UFO linear attention: qkv = x@Wqkv; kv = k^T v per head; xnorm(kv), xnorm(q);
// out = q_n @ kv_n; final = out @ W_o + b_o.
// B=4, N=4096, DIM=1024, H=16, Dh=64.  All big matmuls in bf16 MFMA.
// R2: q-norm fused into GEMM1 epilogue; R5: fold Wo into kvn (Mt per batch).
// R7-R11 findings: MfmaUtil pinned 38-41% across 4-ring/k-slice-dbuf/m201-
//   rhythm/2-blocks-per-CU. R11 (2 blk/CU, occupancy 2x) changed NOTHING ->
//   LDS read BW is per-CU shared; TLP can't hide it; narrower BN raised
//   bytes/FLOP and regressed. GEMM structure frozen at R9 (best: 106.4us).
// R12: R9-exact revert + issue-reduction only:
//   (a) pair-unrolled K-loop -> all LDS buffer indices compile-time;
//   (b) staging addresses hoisted (4 base ptrs + LDS offsets per thread,
//       per-stage addr = base + small const) killing per-call 64-bit muls.
// ---------------------------------------------------------------------------

typedef __bf16 bf16;
typedef bf16  bf16x8 __attribute__((ext_vector_type(8)));
typedef bf16  bf16x4 __attribute__((ext_vector_type(4)));
typedef float f32x4  __attribute__((ext_vector_type(4)));

#define BATCH   4
#define SEQ     4096
#define DIM     1024
#define HEADS   16
#define DHEAD   64
#define MTOK    (BATCH*SEQ)          // 16384
#define N_QKV   (3*DIM)              // 3072
#define NSPLIT  16                   // kv einsum n-splits

#define NB_PACK (MTOK*DIM/(8*256))   // 8192
#define NB_T1   ((N_QKV/32)*(DIM/32))// 3072
#define NB_T2   ((DIM/32)*(DIM/32))  // 1024

typedef __attribute__((address_space(1))) const void gas_v;
typedef __attribute__((address_space(3))) void las_v;

__device__ __forceinline__ void gld_lds16(const void* g, void* l) {
  __builtin_amdgcn_global_load_lds((gas_v*)g, (las_v*)l, 16, 0, 0);
}

template <int VMN>
__device__ __forceinline__ void vmwait() {
  if constexpr (VMN == 4) asm volatile("s_waitcnt vmcnt(4)" ::: "memory");
  else if constexpr (VMN == 0) asm volatile("s_waitcnt vmcnt(0)" ::: "memory");
}

#define PH_BAR() __builtin_amdgcn_s_barrier()

// ---------------------------------------------------------------------------
// prep: [0,8192) pack x->bf16 ; [8192,11264) transpose Wqkv ; rest Wo.
// ---------------------------------------------------------------------------
__global__ __launch_bounds__(256) void prep(const float* __restrict__ x,
                                            const float* __restrict__ Wqkv,
                                            const float* __restrict__ Wo,
                                            bf16* __restrict__ xb,
                                            bf16* __restrict__ WqT,
                                            bf16* __restrict__ WoT) {
  const int bid = blockIdx.x;
  const int t   = threadIdx.x;
  if (bid < NB_PACK) {
    size_t i = (size_t)bid * 256 + t;
    f32x4 a = *(const f32x4*)&x[i * 8];
    f32x4 b = *(const f32x4*)&x[i * 8 + 4];
    bf16x8 o = {(bf16)a.x, (bf16)a.y, (bf16)a.z, (bf16)a.w,
                (bf16)b.x, (bf16)b.y, (bf16)b.z, (bf16)b.w};
    *(bf16x8*)&xb[i * 8] = o;
    return;
  }
  __shared__ float tile[32][33];
  const float* in; bf16* out; int R, C, bx, by;
  if (bid < NB_PACK + NB_T1) {
    int tid = bid - NB_PACK;
    in = Wqkv; out = WqT; R = DIM; C = N_QKV;
    bx = tid % (N_QKV / 32); by = tid / (N_QKV / 32);
  } else {
    int tid = bid - NB_PACK - NB_T1;
    in = Wo; out = WoT; R = DIM; C = DIM;
    bx = tid & 31; by = tid >> 5;
  }
  int c0 = bx * 32, r0 = by * 32;
  int tx = t & 31, ty = t >> 5;    // 32 x 8
#pragma unroll
  for (int i = 0; i < 32; i += 8)
    tile[ty + i][tx] = in[(size_t)(r0 + ty + i) * C + c0 + tx];
  __syncthreads();
#pragma unroll
  for (int i = 0; i < 32; i += 8)
    out[(size_t)(c0 + ty + i) * R + r0 + tx] = (bf16)tile[tx][ty + i];
}

// ---------------------------------------------------------------------------
// gemm256: C[M,N] = A[M,K] * Bt[N,K]^T  (bf16 in, fp32 acc).
// 256x256 tile, BK=64, 512 thr (8 waves as 2Mx4N), 2-dbuf k-slice LDS
// (128 KiB), 4 phases/K-tile, vmcnt(4) twice per tile (R9 structure).
// MODE 1: qkv GEMM; q -> fused xnorm -> bf16 qn; k,v -> bf16.
// MODE 2: final GEMM; Bt is per-batch (Mt_b), +bias, fp32 out.
// ---------------------------------------------------------------------------
template <int MODE>
__global__ __launch_bounds__(512) void gemm256(
    const bf16* __restrict__ A, const bf16* __restrict__ Bt, int N, int K,
    float* __restrict__ C, const float* __restrict__ bias,
    const float* __restrict__ gamma,
    bf16* __restrict__ qn, bf16* __restrict__ kb, bf16* __restrict__ vb) {
  // [dbuf][op A/B][k-slice][256 rows x 32 k]  = 128 KiB
  __shared__ bf16 lds[2][2][2][256 * 32];
  const int t    = threadIdx.x;
  const int lane = t & 63;
  const int wv   = t >> 6;        // 8 waves
  const int wr   = wv >> 2;       // 0..1  -> rows wr*128..+128
  const int wc   = wv & 3;        // 0..3  -> cols wc*64..+64

  // T1: bijective XCD-chunked swizzle (nwg % 8 == 0 for both grids).
  const int GX  = gridDim.x;
  const int nwg = GX * gridDim.y;
  int lin = blockIdx.y * GX + blockIdx.x;
  lin = (lin & 7) * (nwg >> 3) + (lin >> 3);
  const int m0 = (lin / GX) * 256;
  const int n0 = (lin % GX) * 256;

  const int lr   = lane & 15;     // row within 16x16 tile
  const int ks   = lane >> 4;     // 8-elem k-chunk within 32-k slice

  if (MODE == 2) Bt += (size_t)(m0 >> 12) * DIM * DIM;   // per-batch fold

  // fragment LDS offsets within a slice (chunk ^= (row>>1)&3 on 16B chunks)
  int aoff[8], boff[4];
#pragma unroll
  for (int i = 0; i < 8; i++) {
    int ra  = wr * 128 + i * 16 + lr;
    aoff[i] = ra * 32 + ((ks ^ ((ra >> 1) & 3)) * 8);
  }
#pragma unroll
  for (int j = 0; j < 4; j++) {
    int rb  = wc * 64 + j * 16 + lr;
    boff[j] = rb * 32 + ((ks ^ ((rb >> 1) & 3)) * 8);
  }

  // R12(b): hoisted per-thread staging bases (swizzle folded into base).
  const int srow = t >> 2;                                   // 0..127
  const int sseg = t & 3;
  const int swz0 = (sseg ^ ((srow >> 1) & 3)) * 8;           // row srow
  const int swz1 = (sseg ^ (((srow + 128) >> 1) & 3)) * 8;   // row srow+128
  const bf16* aB0 = A  + (size_t)(m0 + srow) * K + swz0;
  const bf16* aB1 = A  + (size_t)(m0 + 128 + srow) * K + swz1;
  const bf16* bB0 = Bt + (size_t)(n0 + srow) * K + swz0;
  const bf16* bB1 = Bt + (size_t)(n0 + 128 + srow) * K + swz1;
  const int ldsOff0 = srow * 32 + sseg * 8;
  const int ldsOff1 = (128 + srow) * 32 + sseg * 8;

  // stage one 256x32 half-slice (16 KB): 2 gld_lds16 per thread
  auto stage = [&](int op, int sl, int bufi, int tt) {
    const int ko = tt * 64 + sl * 32;
    if (op == 0) {
      gld_lds16(aB0 + ko, &lds[bufi][0][sl][ldsOff0]);
      gld_lds16(aB1 + ko, &lds[bufi][0][sl][ldsOff1]);
    } else {
      gld_lds16(bB0 + ko, &lds[bufi][1][sl][ldsOff0]);
      gld_lds16(bB1 + ko, &lds[bufi][1][sl][ldsOff1]);
    }
  };

  f32x4 acc[8][4];
#pragma unroll
  for (int i = 0; i < 8; i++)
#pragma unroll
    for (int j = 0; j < 4; j++) acc[i][j] = {0.f, 0.f, 0.f, 0.f};

  bf16x8 af[4], bfv[4];

// one phase: (4 A-frag rows IBASE..IBASE+3) x (all 4 B-frags) x one k-slice.
// READB: load B frags for this slice (first i-half); else reuse.
// DOST: stage (SOP, SSL) slice of tile STT into buffer BB^1.
#define PHASE(IBASE, READB, SL, BB, DOST, SOP, SSL, STT)                      \
  {                                                                           \
    const bf16* sA = &lds[BB][0][SL][0];                                      \
    const bf16* sB = &lds[BB][1][SL][0];                                      \
    if (READB) {                                                              \
      _Pragma("unroll") for (int j = 0; j < 4; j++)                           \
          bfv[j] = *(const bf16x8*)&sB[boff[j]];                              \
    }                                                                         \
    _Pragma("unroll") for (int i = 0; i < 4; i++)                             \
        af[i] = *(const bf16x8*)&sA[aoff[(IBASE) + i]];                       \
    if (DOST) stage(SOP, SSL, (BB) ^ 1, STT);                                 \
    __builtin_amdgcn_s_setprio(1);                                            \
    _Pragma("unroll") for (int i = 0; i < 4; i++)                             \
      _Pragma("unroll") for (int j = 0; j < 4; j++)                           \
          acc[(IBASE) + i][j] = __builtin_amdgcn_mfma_f32_16x16x32_bf16(      \
              af[i], bfv[j], acc[(IBASE) + i][j], 0, 0, 0);                   \
    __builtin_amdgcn_s_setprio(0);                                            \
  }

// one K-tile (R9 rhythm): 4 phases, 2 barriers, vmcnt(4) before each barrier.
#define TILE(BB, DOST, STT)                                                   \
  PHASE(0, 1, 0, BB, DOST, 0, 0, STT);                                        \
  PHASE(4, 0, 0, BB, DOST, 1, 0, STT);                                        \
  vmwait<4>();                                                                \
  PH_BAR();                                                                   \
  PHASE(0, 1, 1, BB, DOST, 0, 1, STT);                                        \
  PHASE(4, 0, 1, BB, DOST, 1, 1, STT);                                        \
  vmwait<4>();                                                                \
  PH_BAR();

  const int NT = K >> 6;          // 16 for K=1024 (even, >= 4)
  // prologue: stage tile 0 (A-k0, B-k0, A-k1, B-k1); k0 resident after
  // vmcnt(4); k1 fenced at the mid-tile vmcnt of tile 0.
  stage(0, 0, 0, 0); stage(1, 0, 0, 0);
  stage(0, 1, 0, 0); stage(1, 1, 0, 0);
  vmwait<4>();
  __builtin_amdgcn_s_barrier();

  // pair-unrolled main loop: buffer indices compile-time (R12(a)).
  // tiles tt (buf0) and tt+1 (buf1), staging tt+1 and tt+2.
  for (int tt = 0; tt + 3 < NT; tt += 2) {
    TILE(0, 1, tt + 1)
    TILE(1, 1, tt + 2)
  }
  TILE(0, 1, NT - 1)              // tile NT-2 (buf0), stages tile NT-1
  {                               // tile NT-1 (buf1): no stages, drain
    PHASE(0, 1, 0, 1, 0, 0, 0, 0);
    PHASE(4, 0, 0, 1, 0, 0, 0, 0);
    vmwait<0>();
    PH_BAR();
    PHASE(0, 1, 1, 1, 0, 0, 0, 0);
    PHASE(4, 0, 1, 1, 0, 0, 0, 0);
  }
#undef TILE
#undef PHASE

  // epilogue: C layout col=lane&15, row=(lane>>4)*4+reg  (m89-verified)
  const int crow0 = m0 + wr * 128 + (lane >> 4) * 4;

  if (MODE == 2) {
    const int ccol0 = n0 + wc * 64 + lr;
#pragma unroll
    for (int i = 0; i < 8; i++)
#pragma unroll
      for (int j = 0; j < 4; j++) {
        int col = ccol0 + j * 16;
#pragma unroll
        for (int r = 0; r < 4; r++)
          C[(size_t)(crow0 + i * 16 + r) * N + col] = acc[i][j][r] + bias[col];
      }
  } else {
    const int seg = n0 >> 10;           // block-uniform: 0=q, 1=k, 2=v
    if (seg == 0) {
      // fused q-norm: this wave's 64 cols are exactly head h
      const int h    = (n0 + wc * 64) >> 6;
      const float g  = gamma[h];
      const int col0 = n0 + wc * 64 + lr;
#pragma unroll
      for (int i = 0; i < 8; i++)
#pragma unroll
        for (int r = 0; r < 4; r++) {
          float p = acc[i][0][r] * acc[i][0][r] + acc[i][1][r] * acc[i][1][r]
                  + acc[i][2][r] * acc[i][2][r] + acc[i][3][r] * acc[i][3][r];
          p += __shfl_xor(p, 1);
          p += __shfl_xor(p, 2);
          p += __shfl_xor(p, 4);
          p += __shfl_xor(p, 8);        // 16 lanes = the head's 64 cols
          float sc = g * rsqrtf(p);
          size_t rb = (size_t)(crow0 + i * 16 + r) * DIM + col0;
#pragma unroll
          for (int j = 0; j < 4; j++)
            qn[rb + j * 16] = (bf16)(acc[i][j][r] * sc);
        }
    } else {
      bf16* dst = (seg == 1) ? kb : vb;
      const int ccol0 = (n0 - (seg << 10)) + wc * 64 + lr;
#pragma unroll
      for (int i = 0; i < 8; i++)
#pragma unroll
        for (int j = 0; j < 4; j++) {
          int col = ccol0 + j * 16;
#pragma unroll
          for (int r = 0; r < 4; r++)
            dst[(size_t)(crow0 + i * 16 + r) * DIM + col] = (bf16)acc[i][j][r];
        }
    }
  }
}

// ---------------------------------------------------------------------------
// kv partials. grid (NSPLIT, 64bh). fp32 outer-product, 4x4 acc/thread.
// ---------------------------------------------------------------------------
__global__ __launch_bounds__(256) void kv_partial(const bf16* __restrict__ kb,
                                                  const bf16* __restrict__ vb,
                                                  float* __restrict__ part) {
  __shared__ float lK[32 * 64];
  __shared__ float lV[32 * 64];
  const int t  = threadIdx.x;
  const int s  = blockIdx.x;
  const int bh = blockIdx.y;
  const int b  = bh >> 4, h = bh & 15;
  const size_t base = ((size_t)b * SEQ + s * (SEQ / NSPLIT)) * DIM + h * DHEAD;
  const int d0 = (t & 15) * 4, e0 = (t >> 4) * 4;
  const int rr = t >> 3, cc = (t & 7) * 8;

  float acc[4][4];
#pragma unroll
  for (int a = 0; a < 4; a++)
#pragma unroll
    for (int q = 0; q < 4; q++) acc[a][q] = 0.f;

  for (int nt = 0; nt < (SEQ / NSPLIT) / 32; nt++) {
    size_t g = base + (size_t)(nt * 32 + rr) * DIM + cc;
    bf16x8 k8 = *(const bf16x8*)(kb + g);
    bf16x8 v8 = *(const bf16x8*)(vb + g);
    f32x4 klo = {(float)k8[0], (float)k8[1], (float)k8[2], (float)k8[3]};
    f32x4 khi = {(float)k8[4], (float)k8[5], (float)k8[6], (float)k8[7]};
    f32x4 vlo = {(float)v8[0], (float)v8[1], (float)v8[2], (float)v8[3]};
    f32x4 vhi = {(float)v8[4], (float)v8[5], (float)v8[6], (float)v8[7]};
    *(f32x4*)&lK[rr * 64 + cc]     = klo;
    *(f32x4*)&lK[rr * 64 + cc + 4] = khi;
    *(f32x4*)&lV[rr * 64 + cc]     = vlo;
    *(f32x4*)&lV[rr * 64 + cc + 4] = vhi;
    __syncthreads();
#pragma unroll 8
    for (int nn = 0; nn < 32; nn++) {
      f32x4 kk = *(const f32x4*)&lK[nn * 64 + d0];
      f32x4 vv = *(const f32x4*)&lV[nn * 64 + e0];
#pragma unroll
      for (int a = 0; a < 4; a++)
#pragma unroll
        for (int q = 0; q < 4; q++) acc[a][q] += kk[a] * vv[q];
    }
    __syncthreads();
  }
  float* pb = part + ((size_t)bh * NSPLIT + s) * 4096;
#pragma unroll
  for (int a = 0; a < 4; a++) {
    f32x4 o = {acc[a][0], acc[a][1], acc[a][2], acc[a][3]};
    *(f32x4*)&pb[(d0 + a) * 64 + e0] = o;
  }
}

// ---------------------------------------------------------------------------
// kv_norm: reduce partials, row-norm over e, write kvn[bh][d][e] bf16
// ---------------------------------------------------------------------------
__global__ __launch_bounds__(256) void kv_norm(const float* __restrict__ part,
                                               const float* __restrict__ gamma,
                                               bf16* __restrict__ kvn) {
  const int t   = threadIdx.x;
  const int bh  = blockIdx.x >> 2;
  const int h   = bh & 15;
  const int d   = (blockIdx.x & 3) * 16 + (t >> 4);
  const int e0  = (t & 15) * 4;
  f32x4 v = {0.f, 0.f, 0.f, 0.f};
  for (int s = 0; s < NSPLIT; s++) {
    f32x4 a = *(const f32x4*)(part + ((size_t)bh * NSPLIT + s) * 4096 + d * 64 + e0);
    v.x += a.x; v.y += a.y; v.z += a.z; v.w += a.w;
  }
  float ss = v.x * v.x + v.y * v.y + v.z * v.z + v.w * v.w;
  ss += __shfl_xor(ss, 1);
  ss += __shfl_xor(ss, 2);
  ss += __shfl_xor(ss, 4);
  ss += __shfl_xor(ss, 8);          // 16 consecutive lanes share d
  float scale = gamma[h] * rsqrtf(ss);
  bf16x4 o = {(bf16)(v.x * scale), (bf16)(v.y * scale),
              (bf16)(v.z * scale), (bf16)(v.w * scale)};
  *(bf16x4*)&kvn[(size_t)bh * 4096 + d * 64 + e0] = o;
}

// ---------------------------------------------------------------------------
// mfold: Mt[b][n][h*64+d] = sum_e WoT[n][h*64+e] * kvn[bh][d][e]
// ---------------------------------------------------------------------------
__global__ __launch_bounds__(256) void mfold(const bf16* __restrict__ WoT,
                                             const bf16* __restrict__ kvn,
                                             bf16* __restrict__ Mt) {
  __shared__ bf16 lA[128 * 64];   // WoT tile: 128 n-rows x 64 e
  __shared__ bf16 lB[64 * 64];    // kvn_h: 64 d x 64 e
  const int t    = threadIdx.x;
  const int lane = t & 63;
  const int wv   = t >> 6;
  const int bh   = blockIdx.y;
  const int b    = bh >> 4, h = bh & 15;
  const int n0   = blockIdx.x * 128;

#pragma unroll
  for (int p = 0; p < 4; p++) {
    int c = p * 256 + t;
    int row = c >> 3, seg = c & 7;
    int gsk = seg ^ (row & 7);
    gld_lds16(WoT + (size_t)(n0 + row) * DIM + h * 64 + gsk * 8,
              &lA[row * 64 + seg * 8]);
  }
#pragma unroll
  for (int p = 0; p < 2; p++) {
    int c = p * 256 + t;
    int row = c >> 3, seg = c & 7;
    int gsk = seg ^ (row & 7);
    gld_lds16(kvn + (size_t)bh * 4096 + row * 64 + gsk * 8,
              &lB[row * 64 + seg * 8]);
  }
  __syncthreads();

  const int lr = lane & 15, ks = lane >> 4;
  f32x4 acc[2][4];
#pragma unroll
  for (int i = 0; i < 2; i++)
#pragma unroll
    for (int j = 0; j < 4; j++) acc[i][j] = {0.f, 0.f, 0.f, 0.f};

#pragma unroll
  for (int kk = 0; kk < 2; kk++) {
    bf16x8 af[2], bkv[4];
#pragma unroll
    for (int i = 0; i < 2; i++) {
      int row = wv * 32 + i * 16 + lr;
      int seg = (kk * 4 + ks) ^ (row & 7);
      af[i] = *(const bf16x8*)&lA[row * 64 + seg * 8];
    }
#pragma unroll
    for (int j = 0; j < 4; j++) {
      int row = j * 16 + lr;
      int seg = (kk * 4 + ks) ^ (row & 7);
      bkv[j] = *(const bf16x8*)&lB[row * 64 + seg * 8];
    }
#pragma unroll
    for (int i = 0; i < 2; i++)
#pragma unroll
      for (int j = 0; j < 4; j++)
        acc[i][j] = __builtin_amdgcn_mfma_f32_16x16x32_bf16(af[i], bkv[j],
                                                            acc[i][j], 0, 0, 0);
  }

  // C layout: row(n) = wv*32 + i*16 + ks*4 + r ; col(d) = j*16 + lr
  bf16* mb = Mt + (size_t)b * DIM * DIM;
#pragma unroll
  for (int i = 0; i < 2; i++)
#pragma unroll
    for (int j = 0; j < 4; j++) {
      int col = h * 64 + j * 16 + lr;
#pragma unroll
      for (int r = 0; r < 4; r++) {
        int row = n0 + wv * 32 + i * 16 + ks * 4 + r;
        mb[(size_t)row * DIM + col] = (bf16)acc[i][j][r];
      }
    }
}

// ---------------------------------------------------------------------------
extern "C" void kernel_launch(void* const* d_in, const int* in_sizes, int n_in,
                              void* d_out, int out_size, void* d_ws,
                              size_t ws_size, hipStream_t stream) {
  const float* x     = (const float*)d_in[0];
  const float* Wqkv  = (const float*)d_in[1];
  const float* Wo    = (const float*)d_in[2];
  const float* bo    = (const float*)d_in[3];
  const float* gamma = (const float*)d_in[4];
  float* out = (float*)d_out;

  char* ws = (char*)d_ws;
  size_t off = 0;
  bf16*  xb   = (bf16*)(ws + off);  off += (size_t)MTOK * DIM * 2;        // 32 MB
  bf16*  WqT  = (bf16*)(ws + off);  off += (size_t)N_QKV * DIM * 2;       //  6 MB
  bf16*  WoT  = (bf16*)(ws + off);  off += (size_t)DIM * DIM * 2;         //  2 MB
  bf16*  kvn  = (bf16*)(ws + off);  off += (size_t)64 * 4096 * 2;         // .5 MB
  bf16*  qn   = (bf16*)(ws + off);  off += (size_t)MTOK * DIM * 2;        // 32 MB
  bf16*  kb   = (bf16*)(ws + off);  off += (size_t)MTOK * DIM * 2;        // 32 MB
  bf16*  vb   = (bf16*)(ws + off);  off += (size_t)MTOK * DIM * 2;        // 32 MB
  float* part = (float*)(ws + off); off += (size_t)64 * NSPLIT * 4096 * 4;// 16 MB
  bf16*  Mt   = (bf16*)(ws + off);  off += (size_t)BATCH * DIM * DIM * 2; //  8 MB

  prep<<<dim3(NB_PACK + NB_T1 + NB_T2), dim3(256), 0, stream>>>(
      x, Wqkv, Wo, xb, WqT, WoT);

  gemm256<1><<<dim3(N_QKV / 256, MTOK / 256), dim3(512), 0, stream>>>(
      xb, WqT, N_QKV, DIM, nullptr, nullptr, gamma, qn, kb, vb);

  kv_partial<<<dim3(NSPLIT, 64), dim3(256), 0, stream>>>(kb, vb, part);
  kv_norm<<<dim3(256), dim3(256), 0, stream>>>(part, gamma, kvn);

  mfold<<<dim3(DIM / 128, 64), dim3(256), 0, stream>>>(WoT, kvn, Mt);

  gemm256<2><<<dim3(DIM / 256, MTOK / 256), dim3(512), 0, stream>>>(
      qn, Mt, DIM, DIM, out, bo, nullptr, nullptr, nullptr, nullptr);
}

// Round 9
// 307.703 us; speedup vs baseline: 1.0613x; 1.0346x over previous
//
#include <hip/hip_runtime.h>

// ---------------------------------------------------------------------------
// UFO linear attention: qkv = x@Wqkv; kv = k^T v per head; xnorm(kv), xnorm(q);
// out = q_n @ kv_n; final = out @ W_o + b_o.
// B=4, N=4096, DIM=1024, H=16, Dh=64.  All big matmuls in bf16 MFMA.
// R2: q-norm fused into GEMM1 epilogue; R5: fold Wo into kvn (Mt per batch).
// R7-R12 GEMM history: 38-41% MfmaUtil across 6 structural variants
//   (4-ring vmcnt8 869TF / -schedbar+XCD / BK64 k-slice dbuf 969TF best /
//    m201 rhythm regress / 2-blk-CU TLP null / addr-hoist+unroll regress).
//   Conclusion: R9 structure is this session's GEMM plateau. FROZEN.
// R13: revert gemm256 to R9-exact (106.4us measured); NSPLIT 16->8 halves
//   the part intermediate (-8MB write, -8MB read). No other changes.
// R14/R15: identical resubmits (benches died on container infra both times:
//   "MI355X container failed twice", nothing ran, no counters).
// ---------------------------------------------------------------------------

typedef __bf16 bf16;
typedef bf16  bf16x8 __attribute__((ext_vector_type(8)));
typedef bf16  bf16x4 __attribute__((ext_vector_type(4)));
typedef float f32x4  __attribute__((ext_vector_type(4)));

#define BATCH   4
#define SEQ     4096
#define DIM     1024
#define HEADS   16
#define DHEAD   64
#define MTOK    (BATCH*SEQ)          // 16384
#define N_QKV   (3*DIM)              // 3072
#define NSPLIT  8                    // kv einsum n-splits (R13: 16->8)

#define NB_PACK (MTOK*DIM/(8*256))   // 8192
#define NB_T1   ((N_QKV/32)*(DIM/32))// 3072
#define NB_T2   ((DIM/32)*(DIM/32))  // 1024

typedef __attribute__((address_space(1))) const void gas_v;
typedef __attribute__((address_space(3))) void las_v;

__device__ __forceinline__ void gld_lds16(const void* g, void* l) {
  __builtin_amdgcn_global_load_lds((gas_v*)g, (las_v*)l, 16, 0, 0);
}

template <int VMN>
__device__ __forceinline__ void vmwait() {
  if constexpr (VMN == 4) asm volatile("s_waitcnt vmcnt(4)" ::: "memory");
  else if constexpr (VMN == 0) asm volatile("s_waitcnt vmcnt(0)" ::: "memory");
}

#define PH_BAR() __builtin_amdgcn_s_barrier()

// ---------------------------------------------------------------------------
// prep: [0,8192) pack x->bf16 ; [8192,11264) transpose Wqkv ; rest Wo.
// ---------------------------------------------------------------------------
__global__ __launch_bounds__(256) void prep(const float* __restrict__ x,
                                            const float* __restrict__ Wqkv,
                                            const float* __restrict__ Wo,
                                            bf16* __restrict__ xb,
                                            bf16* __restrict__ WqT,
                                            bf16* __restrict__ WoT) {
  const int bid = blockIdx.x;
  const int t   = threadIdx.x;
  if (bid < NB_PACK) {
    size_t i = (size_t)bid * 256 + t;
    f32x4 a = *(const f32x4*)&x[i * 8];
    f32x4 b = *(const f32x4*)&x[i * 8 + 4];
    bf16x8 o = {(bf16)a.x, (bf16)a.y, (bf16)a.z, (bf16)a.w,
                (bf16)b.x, (bf16)b.y, (bf16)b.z, (bf16)b.w};
    *(bf16x8*)&xb[i * 8] = o;
    return;
  }
  __shared__ float tile[32][33];
  const float* in; bf16* out; int R, C, bx, by;
  if (bid < NB_PACK + NB_T1) {
    int tid = bid - NB_PACK;
    in = Wqkv; out = WqT; R = DIM; C = N_QKV;
    bx = tid % (N_QKV / 32); by = tid / (N_QKV / 32);
  } else {
    int tid = bid - NB_PACK - NB_T1;
    in = Wo; out = WoT; R = DIM; C = DIM;
    bx = tid & 31; by = tid >> 5;
  }
  int c0 = bx * 32, r0 = by * 32;
  int tx = t & 31, ty = t >> 5;    // 32 x 8
#pragma unroll
  for (int i = 0; i < 32; i += 8)
    tile[ty + i][tx] = in[(size_t)(r0 + ty + i) * C + c0 + tx];
  __syncthreads();
#pragma unroll
  for (int i = 0; i < 32; i += 8)
    out[(size_t)(c0 + ty + i) * R + r0 + tx] = (bf16)tile[tx][ty + i];
}

// ---------------------------------------------------------------------------
// gemm256 (R9-exact, FROZEN): C[M,N] = A[M,K] * Bt[N,K]^T  (bf16, fp32 acc).
// 256x256 tile, BK=64, 512 thr (8 waves as 2Mx4N), 2-dbuf k-slice LDS
// (128 KiB), 4 phases/K-tile, vmcnt(4) twice per tile.
// MODE 1: qkv GEMM; q -> fused xnorm -> bf16 qn; k,v -> bf16.
// MODE 2: final GEMM; Bt is per-batch (Mt_b), +bias, fp32 out.
// ---------------------------------------------------------------------------
template <int MODE>
__global__ __launch_bounds__(512) void gemm256(
    const bf16* __restrict__ A, const bf16* __restrict__ Bt, int N, int K,
    float* __restrict__ C, const float* __restrict__ bias,
    const float* __restrict__ gamma,
    bf16* __restrict__ qn, bf16* __restrict__ kb, bf16* __restrict__ vb) {
  // [dbuf][op A/B][k-slice][256 rows x 32 k]  = 128 KiB
  __shared__ bf16 lds[2][2][2][256 * 32];
  const int t    = threadIdx.x;
  const int lane = t & 63;
  const int wv   = t >> 6;        // 8 waves
  const int wr   = wv >> 2;       // 0..1  -> rows wr*128..+128
  const int wc   = wv & 3;        // 0..3  -> cols wc*64..+64

  // T1: bijective XCD-chunked swizzle (nwg % 8 == 0 for both grids).
  const int GX  = gridDim.x;
  const int nwg = GX * gridDim.y;
  int lin = blockIdx.y * GX + blockIdx.x;
  lin = (lin & 7) * (nwg >> 3) + (lin >> 3);
  const int m0 = (lin / GX) * 256;
  const int n0 = (lin % GX) * 256;

  const int lr   = lane & 15;     // row within 16x16 tile
  const int ks   = lane >> 4;     // 8-elem k-chunk within 32-k slice

  if (MODE == 2) Bt += (size_t)(m0 >> 12) * DIM * DIM;   // per-batch fold

  // fragment LDS offsets within a slice (chunk ^= (row>>1)&3 on 16B chunks)
  int aoff[8], boff[4];
#pragma unroll
  for (int i = 0; i < 8; i++) {
    int ra  = wr * 128 + i * 16 + lr;
    aoff[i] = ra * 32 + ((ks ^ ((ra >> 1) & 3)) * 8);
  }
#pragma unroll
  for (int j = 0; j < 4; j++) {
    int rb  = wc * 64 + j * 16 + lr;
    boff[j] = rb * 32 + ((ks ^ ((rb >> 1) & 3)) * 8);
  }

  const bf16* Asrc = A;
  const bf16* Bsrc = Bt;
  // stage one 256x32 half-slice (16 KB): 2 gld_lds16 per thread
  auto stage = [&](int op, int sl, int bufi, int tt) {
    const bf16* src = op ? Bsrc : Asrc;
    const int   rb0 = op ? n0 : m0;
    const int   k0  = tt * 64 + sl * 32;
#pragma unroll
    for (int p = 0; p < 2; ++p) {
      int row  = p * 128 + (t >> 2);
      int gseg = (t & 3) ^ ((row >> 1) & 3);
      gld_lds16(src + (size_t)(rb0 + row) * K + k0 + gseg * 8,
                &lds[bufi][op][sl][row * 32 + (t & 3) * 8]);
    }
  };

  f32x4 acc[8][4];
#pragma unroll
  for (int i = 0; i < 8; i++)
#pragma unroll
    for (int j = 0; j < 4; j++) acc[i][j] = {0.f, 0.f, 0.f, 0.f};

  bf16x8 af[4], bfv[4];

// one phase: (4 A-frag rows IBASE..IBASE+3) x (all 4 B-frags) x one k-slice.
// READB: load B frags for this slice (first i-half); else reuse.
// DOST: stage (SOP, SSL) slice of tile STT into buffer BB^1.
#define PHASE(IBASE, READB, SL, BB, DOST, SOP, SSL, STT)                      \
  {                                                                           \
    const bf16* sA = &lds[BB][0][SL][0];                                      \
    const bf16* sB = &lds[BB][1][SL][0];                                      \
    if (READB) {                                                              \
      _Pragma("unroll") for (int j = 0; j < 4; j++)                           \
          bfv[j] = *(const bf16x8*)&sB[boff[j]];                              \
    }                                                                         \
    _Pragma("unroll") for (int i = 0; i < 4; i++)                             \
        af[i] = *(const bf16x8*)&sA[aoff[(IBASE) + i]];                       \
    if (DOST) stage(SOP, SSL, (BB) ^ 1, STT);                                 \
    __builtin_amdgcn_s_setprio(1);                                            \
    _Pragma("unroll") for (int i = 0; i < 4; i++)                             \
      _Pragma("unroll") for (int j = 0; j < 4; j++)                           \
          acc[(IBASE) + i][j] = __builtin_amdgcn_mfma_f32_16x16x32_bf16(      \
              af[i], bfv[j], acc[(IBASE) + i][j], 0, 0, 0);                   \
    __builtin_amdgcn_s_setprio(0);                                            \
  }

  const int NT = K >> 6;          // 16 for K=1024
  // prologue: stage tile 0 (4 half-slices, 8 loads); k0 resident after
  // vmcnt(4); k1 still in flight (fenced at mid-tile).
  stage(0, 0, 0, 0); stage(1, 0, 0, 0);
  stage(0, 1, 0, 0); stage(1, 1, 0, 0);
  vmwait<4>();
  PH_BAR();

  for (int tt = 0; tt < NT - 1; ++tt) {
    const int bb = tt & 1;
    PHASE(0, 1, 0, bb, 1, 0, 0, tt + 1);   // P0: i0-3 k0 | stage A-k0(t+1)
    PHASE(4, 0, 0, bb, 1, 1, 0, tt + 1);   // P1: i4-7 k0 | stage B-k0(t+1)
    vmwait<4>();                           // this tile's k1 resident
    PH_BAR();
    PHASE(0, 1, 1, bb, 1, 0, 1, tt + 1);   // P2: i0-3 k1 | stage A-k1(t+1)
    PHASE(4, 0, 1, bb, 1, 1, 1, tt + 1);   // P3: i4-7 k1 | stage B-k1(t+1)
    vmwait<4>();                           // next tile's k0 resident
    PH_BAR();
  }
  {                                        // epilogue tile NT-1 (no stages)
    const int bb = (NT - 1) & 1;
    PHASE(0, 1, 0, bb, 0, 0, 0, 0);
    PHASE(4, 0, 0, bb, 0, 0, 0, 0);
    vmwait<0>();
    PH_BAR();
    PHASE(0, 1, 1, bb, 0, 0, 0, 0);
    PHASE(4, 0, 1, bb, 0, 0, 0, 0);
  }
#undef PHASE

  // epilogue: C layout col=lane&15, row=(lane>>4)*4+reg  (m89-verified)
  const int crow0 = m0 + wr * 128 + (lane >> 4) * 4;

  if (MODE == 2) {
    const int ccol0 = n0 + wc * 64 + lr;
#pragma unroll
    for (int i = 0; i < 8; i++)
#pragma unroll
      for (int j = 0; j < 4; j++) {
        int col = ccol0 + j * 16;
#pragma unroll
        for (int r = 0; r < 4; r++)
          C[(size_t)(crow0 + i * 16 + r) * N + col] = acc[i][j][r] + bias[col];
      }
  } else {
    const int seg = n0 >> 10;           // block-uniform: 0=q, 1=k, 2=v
    if (seg == 0) {
      // fused q-norm: this wave's 64 cols are exactly head h
      const int h    = (n0 + wc * 64) >> 6;
      const float g  = gamma[h];
      const int col0 = n0 + wc * 64 + lr;
#pragma unroll
      for (int i = 0; i < 8; i++)
#pragma unroll
        for (int r = 0; r < 4; r++) {
          float p = acc[i][0][r] * acc[i][0][r] + acc[i][1][r] * acc[i][1][r]
                  + acc[i][2][r] * acc[i][2][r] + acc[i][3][r] * acc[i][3][r];
          p += __shfl_xor(p, 1);
          p += __shfl_xor(p, 2);
          p += __shfl_xor(p, 4);
          p += __shfl_xor(p, 8);        // 16 lanes = the head's 64 cols
          float sc = g * rsqrtf(p);
          size_t rb = (size_t)(crow0 + i * 16 + r) * DIM + col0;
#pragma unroll
          for (int j = 0; j < 4; j++)
            qn[rb + j * 16] = (bf16)(acc[i][j][r] * sc);
        }
    } else {
      bf16* dst = (seg == 1) ? kb : vb;
      const int ccol0 = (n0 - (seg << 10)) + wc * 64 + lr;
#pragma unroll
      for (int i = 0; i < 8; i++)
#pragma unroll
        for (int j = 0; j < 4; j++) {
          int col = ccol0 + j * 16;
#pragma unroll
          for (int r = 0; r < 4; r++)
            dst[(size_t)(crow0 + i * 16 + r) * DIM + col] = (bf16)acc[i][j][r];
        }
    }
  }
}

// ---------------------------------------------------------------------------
// kv partials. grid (NSPLIT, 64bh). fp32 outer-product, 4x4 acc/thread.
// ---------------------------------------------------------------------------
__global__ __launch_bounds__(256) void kv_partial(const bf16* __restrict__ kb,
                                                  const bf16* __restrict__ vb,
                                                  float* __restrict__ part) {
  __shared__ float lK[32 * 64];
  __shared__ float lV[32 * 64];
  const int t  = threadIdx.x;
  const int s  = blockIdx.x;
  const int bh = blockIdx.y;
  const int b  = bh >> 4, h = bh & 15;
  const size_t base = ((size_t)b * SEQ + s * (SEQ / NSPLIT)) * DIM + h * DHEAD;
  const int d0 = (t & 15) * 4, e0 = (t >> 4) * 4;
  const int rr = t >> 3, cc = (t & 7) * 8;

  float acc[4][4];
#pragma unroll
  for (int a = 0; a < 4; a++)
#pragma unroll
    for (int q = 0; q < 4; q++) acc[a][q] = 0.f;

  for (int nt = 0; nt < (SEQ / NSPLIT) / 32; nt++) {
    size_t g = base + (size_t)(nt * 32 + rr) * DIM + cc;
    bf16x8 k8 = *(const bf16x8*)(kb + g);
    bf16x8 v8 = *(const bf16x8*)(vb + g);
    f32x4 klo = {(float)k8[0], (float)k8[1], (float)k8[2], (float)k8[3]};
    f32x4 khi = {(float)k8[4], (float)k8[5], (float)k8[6], (float)k8[7]};
    f32x4 vlo = {(float)v8[0], (float)v8[1], (float)v8[2], (float)v8[3]};
    f32x4 vhi = {(float)v8[4], (float)v8[5], (float)v8[6], (float)v8[7]};
    *(f32x4*)&lK[rr * 64 + cc]     = klo;
    *(f32x4*)&lK[rr * 64 + cc + 4] = khi;
    *(f32x4*)&lV[rr * 64 + cc]     = vlo;
    *(f32x4*)&lV[rr * 64 + cc + 4] = vhi;
    __syncthreads();
#pragma unroll 8
    for (int nn = 0; nn < 32; nn++) {
      f32x4 kk = *(const f32x4*)&lK[nn * 64 + d0];
      f32x4 vv = *(const f32x4*)&lV[nn * 64 + e0];
#pragma unroll
      for (int a = 0; a < 4; a++)
#pragma unroll
        for (int q = 0; q < 4; q++) acc[a][q] += kk[a] * vv[q];
    }
    __syncthreads();
  }
  float* pb = part + ((size_t)bh * NSPLIT + s) * 4096;
#pragma unroll
  for (int a = 0; a < 4; a++) {
    f32x4 o = {acc[a][0], acc[a][1], acc[a][2], acc[a][3]};
    *(f32x4*)&pb[(d0 + a) * 64 + e0] = o;
  }
}

// ---------------------------------------------------------------------------
// kv_norm: reduce partials, row-norm over e, write kvn[bh][d][e] bf16
// ---------------------------------------------------------------------------
__global__ __launch_bounds__(256) void kv_norm(const float* __restrict__ part,
                                               const float* __restrict__ gamma,
                                               bf16* __restrict__ kvn) {
  const int t   = threadIdx.x;
  const int bh  = blockIdx.x >> 2;
  const int h   = bh & 15;
  const int d   = (blockIdx.x & 3) * 16 + (t >> 4);
  const int e0  = (t & 15) * 4;
  f32x4 v = {0.f, 0.f, 0.f, 0.f};
  for (int s = 0; s < NSPLIT; s++) {
    f32x4 a = *(const f32x4*)(part + ((size_t)bh * NSPLIT + s) * 4096 + d * 64 + e0);
    v.x += a.x; v.y += a.y; v.z += a.z; v.w += a.w;
  }
  float ss = v.x * v.x + v.y * v.y + v.z * v.z + v.w * v.w;
  ss += __shfl_xor(ss, 1);
  ss += __shfl_xor(ss, 2);
  ss += __shfl_xor(ss, 4);
  ss += __shfl_xor(ss, 8);          // 16 consecutive lanes share d
  float scale = gamma[h] * rsqrtf(ss);
  bf16x4 o = {(bf16)(v.x * scale), (bf16)(v.y * scale),
              (bf16)(v.z * scale), (bf16)(v.w * scale)};
  *(bf16x4*)&kvn[(size_t)bh * 4096 + d * 64 + e0] = o;
}

// ---------------------------------------------------------------------------
// mfold: Mt[b][n][h*64+d] = sum_e WoT[n][h*64+e] * kvn[bh][d][e]
// ---------------------------------------------------------------------------
__global__ __launch_bounds__(256) void mfold(const bf16* __restrict__ WoT,
                                             const bf16* __restrict__ kvn,
                                             bf16* __restrict__ Mt) {
  __shared__ bf16 lA[128 * 64];   // WoT tile: 128 n-rows x 64 e
  __shared__ bf16 lB[64 * 64];    // kvn_h: 64 d x 64 e
  const int t    = threadIdx.x;
  const int lane = t & 63;
  const int wv   = t >> 6;
  const int bh   = blockIdx.y;
  const int b    = bh >> 4, h = bh & 15;
  const int n0   = blockIdx.x * 128;

#pragma unroll
  for (int p = 0; p < 4; p++) {
    int c = p * 256 + t;
    int row = c >> 3, seg = c & 7;
    int gsk = seg ^ (row & 7);
    gld_lds16(WoT + (size_t)(n0 + row) * DIM + h * 64 + gsk * 8,
              &lA[row * 64 + seg * 8]);
  }
#pragma unroll
  for (int p = 0; p < 2; p++) {
    int c = p * 256 + t;
    int row = c >> 3, seg = c & 7;
    int gsk = seg ^ (row & 7);
    gld_lds16(kvn + (size_t)bh * 4096 + row * 64 + gsk * 8,
              &lB[row * 64 + seg * 8]);
  }
  __syncthreads();

  const int lr = lane & 15, ks = lane >> 4;
  f32x4 acc[2][4];
#pragma unroll
  for (int i = 0; i < 2; i++)
#pragma unroll
    for (int j = 0; j < 4; j++) acc[i][j] = {0.f, 0.f, 0.f, 0.f};

#pragma unroll
  for (int kk = 0; kk < 2; kk++) {
    bf16x8 af[2], bkv[4];
#pragma unroll
    for (int i = 0; i < 2; i++) {
      int row = wv * 32 + i * 16 + lr;
      int seg = (kk * 4 + ks) ^ (row & 7);
      af[i] = *(const bf16x8*)&lA[row * 64 + seg * 8];
    }
#pragma unroll
    for (int j = 0; j < 4; j++) {
      int row = j * 16 + lr;
      int seg = (kk * 4 + ks) ^ (row & 7);
      bkv[j] = *(const bf16x8*)&lB[row * 64 + seg * 8];
    }
#pragma unroll
    for (int i = 0; i < 2; i++)
#pragma unroll
      for (int j = 0; j < 4; j++)
        acc[i][j] = __builtin_amdgcn_mfma_f32_16x16x32_bf16(af[i], bkv[j],
                                                            acc[i][j], 0, 0, 0);
  }

  // C layout: row(n) = wv*32 + i*16 + ks*4 + r ; col(d) = j*16 + lr
  bf16* mb = Mt + (size_t)b * DIM * DIM;
#pragma unroll
  for (int i = 0; i < 2; i++)
#pragma unroll
    for (int j = 0; j < 4; j++) {
      int col = h * 64 + j * 16 + lr;
#pragma unroll
      for (int r = 0; r < 4; r++) {
        int row = n0 + wv * 32 + i * 16 + ks * 4 + r;
        mb[(size_t)row * DIM + col] = (bf16)acc[i][j][r];
      }
    }
}

// ---------------------------------------------------------------------------
extern "C" void kernel_launch(void* const* d_in, const int* in_sizes, int n_in,
                              void* d_out, int out_size, void* d_ws,
                              size_t ws_size, hipStream_t stream) {
  const float* x     = (const float*)d_in[0];
  const float* Wqkv  = (const float*)d_in[1];
  const float* Wo    = (const float*)d_in[2];
  const float* bo    = (const float*)d_in[3];
  const float* gamma = (const float*)d_in[4];
  float* out = (float*)d_out;

  char* ws = (char*)d_ws;
  size_t off = 0;
  bf16*  xb   = (bf16*)(ws + off);  off += (size_t)MTOK * DIM * 2;        // 32 MB
  bf16*  WqT  = (bf16*)(ws + off);  off += (size_t)N_QKV * DIM * 2;       //  6 MB
  bf16*  WoT  = (bf16*)(ws + off);  off += (size_t)DIM * DIM * 2;         //  2 MB
  bf16*  kvn  = (bf16*)(ws + off);  off += (size_t)64 * 4096 * 2;         // .5 MB
  bf16*  qn   = (bf16*)(ws + off);  off += (size_t)MTOK * DIM * 2;        // 32 MB
  bf16*  kb   = (bf16*)(ws + off);  off += (size_t)MTOK * DIM * 2;        // 32 MB
  bf16*  vb   = (bf16*)(ws + off);  off += (size_t)MTOK * DIM * 2;        // 32 MB
  float* part = (float*)(ws + off); off += (size_t)64 * NSPLIT * 4096 * 4;//  8 MB
  bf16*  Mt   = (bf16*)(ws + off);  off += (size_t)BATCH * DIM * DIM * 2; //  8 MB

  prep<<<dim3(NB_PACK + NB_T1 + NB_T2), dim3(256), 0, stream>>>(
      x, Wqkv, Wo, xb, WqT, WoT);

  gemm256<1><<<dim3(N_QKV / 256, MTOK / 256), dim3(512), 0, stream>>>(
      xb, WqT, N_QKV, DIM, nullptr, nullptr, gamma, qn, kb, vb);

  kv_partial<<<dim3(NSPLIT, 64), dim3(256), 0, stream>>>(kb, vb, part);
  kv_norm<<<dim3(256), dim3(256), 0, stream>>>(part, gamma, kvn);

  mfold<<<dim3(DIM / 128, 64), dim3(256), 0, stream>>>(WoT, kvn, Mt);

  gemm256<2><<<dim3(DIM / 256, MTOK / 256), dim3(512), 0, stream>>>(
      qn, Mt, DIM, DIM, out, bo, nullptr, nullptr, nullptr, nullptr);
}